// Round 3
// baseline (215.570 us; speedup 1.0000x reference)
//
#include <hip/hip_runtime.h>
#include <math.h>

#define N_G   64
#define M_N   32
#define FEAT  256
#define POSD  6
#define D     262
#define MSG   128
#define NCLS  7

#define KA_S  424       // LDS buf row stride (shorts): [mv 128 | h 262 | pad]
#define KHW   288       // weight K window over h (262 -> 288)
#define KFULL 416       // full concat K
#define PSTR  320       // paL/pbL row stride (shorts), covers c16*4+64k up to 316

// packed weight sizes (shorts)
#define S_PROJ (528*288)
#define S_MSG  (128*288)
#define S_RZ   (544*416)
#define S_XN   (272*128)
#define S_HN   (272*288)
#define S_RO   (128*288)
#define S_RO2  (16*128)

// workspace float offsets
#define O_WPROJ 0u
#define O_WMSG  76032u
#define O_WRZ   94464u
#define O_WXN   207616u
#define O_WHN   225024u
#define O_WRO   264192u
#define O_WRO2  282624u
#define O_GB    283648u   // 1088 fp32 gate biases [br|bz|bxn|bhn] x 272

typedef __attribute__((ext_vector_type(8))) short short8;
typedef __attribute__((ext_vector_type(4))) short short4v;
typedef __attribute__((ext_vector_type(4))) float floatx4;

#define MFMA __builtin_amdgcn_mfma_f32_16x16x32_bf16

__device__ __forceinline__ short f2bf(float f) {
    union { float f; unsigned u; } v; v.f = f;
    unsigned r = v.u + 0x7FFF + ((v.u >> 16) & 1);   // RNE
    return (short)(r >> 16);
}
__device__ __forceinline__ float bf2f(short s) {
    union { float f; unsigned u; } v;
    v.u = ((unsigned)(unsigned short)s) << 16;
    return v.f;
}
// fast sigmoid/tanh: v_exp_f32 + v_rcp_f32 (~1e-6 rel err, vs bf16-path 5e-3)
__device__ __forceinline__ float sigf(float x) {
    return __builtin_amdgcn_rcpf(1.f + __expf(-x));
}
__device__ __forceinline__ float tanh_fast(float x) {
    float e = __expf(-2.f * fabsf(x));
    float t = (1.f - e) * __builtin_amdgcn_rcpf(1.f + e);
    return copysignf(t, x);
}

// ---------------------------------------------------------------------------
// prep: pack all weights bf16 [n][k] (B^T) with padded/zeroed windows + biases
// ---------------------------------------------------------------------------
__global__ void prep_kernel(const float* __restrict__ w1, const float* __restrict__ msg_w,
                            const float* __restrict__ w_ih, const float* __restrict__ w_hh,
                            const float* __restrict__ ro_w1, const float* __restrict__ ro_w2,
                            const float* __restrict__ b_ih, const float* __restrict__ b_hh,
                            float* __restrict__ ws)
{
    short* wproj = (short*)(ws + O_WPROJ);
    short* wmsg  = (short*)(ws + O_WMSG);
    short* wrz   = (short*)(ws + O_WRZ);
    short* wxn   = (short*)(ws + O_WXN);
    short* whn   = (short*)(ws + O_WHN);
    short* wro   = (short*)(ws + O_WRO);
    short* wro2  = (short*)(ws + O_WRO2);
    float* gb    = ws + O_GB;
    const int TOT_S = S_PROJ + S_MSG + S_RZ + S_XN + S_HN + S_RO + S_RO2;
    const int TOTAL = TOT_S + 1088;
    for (int i = blockIdx.x * blockDim.x + threadIdx.x; i < TOTAL;
         i += gridDim.x * blockDim.x) {
        int idx = i;
        if (idx < S_PROJ) {                       // [528][288]
            int n = idx / 288, k = idx % 288;
            float v = 0.f;
            if (k < D && n < 524)
                v = (n < D) ? w1[n * 524 + k] : w1[(n - D) * 524 + D + k];
            wproj[idx] = f2bf(v);
            continue;
        }
        idx -= S_PROJ;
        if (idx < S_MSG) {                        // [128][288]
            int n = idx / 288, k = idx % 288;
            wmsg[idx] = f2bf(k < D ? msg_w[n * D + k] : 0.f);
            continue;
        }
        idx -= S_MSG;
        if (idx < S_RZ) {                         // [544][416]: rows 0..271 r, 272..543 z
            int g = idx / 416, k = idx % 416;
            int gi = (g < 272) ? 0 : 1;
            int d = g - gi * 272;
            float v = 0.f;
            if (d < D) {
                int row = gi * D + d;
                if (k < 128)            v = w_ih[row * MSG + k];
                else if (k < 128 + D)   v = w_hh[row * D + (k - 128)];
            }
            wrz[idx] = f2bf(v);
            continue;
        }
        idx -= S_RZ;
        if (idx < S_XN) {                         // [272][128]
            int d = idx / 128, k = idx % 128;
            wxn[idx] = f2bf(d < D ? w_ih[(2 * D + d) * MSG + k] : 0.f);
            continue;
        }
        idx -= S_XN;
        if (idx < S_HN) {                         // [272][288]
            int d = idx / 288, k = idx % 288;
            whn[idx] = f2bf((d < D && k < D) ? w_hh[(2 * D + d) * D + k] : 0.f);
            continue;
        }
        idx -= S_HN;
        if (idx < S_RO) {                         // [128][288]
            int n = idx / 288, k = idx % 288;
            wro[idx] = f2bf(k < D ? ro_w1[n * D + k] : 0.f);
            continue;
        }
        idx -= S_RO;
        if (idx < S_RO2) {                        // [16][128]
            int n = idx / 128, k = idx % 128;
            wro2[idx] = f2bf(n < NCLS ? ro_w2[n * MSG + k] : 0.f);
            continue;
        }
        idx -= S_RO2;
        {                                          // gate biases [4][272]
            int seg = idx / 272, d = idx % 272;
            float v = 0.f;
            if (d < D) {
                if (seg == 0)      v = b_ih[d] + b_hh[d];
                else if (seg == 1) v = b_ih[D + d] + b_hh[D + d];
                else if (seg == 2) v = b_ih[2 * D + d];
                else               v = b_hh[2 * D + d];
            }
            gb[idx] = v;
        }
    }
}

// ---------------------------------------------------------------------------
// fused: one block per graph; full forward in LDS.
// Round-3: register-staged weight streams done RIGHT this time:
//  - __launch_bounds__(1024, 4): VGPR cap 128 (16 waves = 4/SIMD; LDS pins
//    1 block/CU anyway). Round-2's bare (1024) made the compiler cap at 64
//    VGPR -> staged arrays spilled to scratch (WRITE_SIZE 13.6 MB).
//  - No array-through-pointer (forces memory); all arrays statically indexed
//    under #pragma unroll.
//  - GRU: full units (both row-halves per wave) so each staged weight tile
//    is consumed twice; z/h streams rotate into the r-regs while MFMAs run.
// ---------------------------------------------------------------------------
__global__ __launch_bounds__(1024, 4) void fused_kernel(
    const float* __restrict__ nodes, const float* __restrict__ pos,
    const int* __restrict__ nrec_g,
    const float* __restrict__ b1g, const float* __restrict__ w2g,
    const float* __restrict__ b2g, const float* __restrict__ msg_bg,
    const float* __restrict__ ro_b1g, const float* __restrict__ ro_b2g,
    const float* __restrict__ ws,
    float* __restrict__ att_out, float* __restrict__ pred)
{
    const short* Wproj = (const short*)(ws + O_WPROJ);
    const short* Wmsg  = (const short*)(ws + O_WMSG);
    const short* Wrz   = (const short*)(ws + O_WRZ);
    const short* Wxn   = (const short*)(ws + O_WXN);
    const short* Whn   = (const short*)(ws + O_WHN);
    const short* Wro   = (const short*)(ws + O_WRO);
    const short* Wro2  = (const short*)(ws + O_WRO2);
    const float* gb    = ws + O_GB;

    __shared__ __align__(16) short bufA[32 * KA_S];
    __shared__ __align__(16) short bufB[32 * KA_S];
    __shared__ __align__(16) short paL[32 * PSTR];
    __shared__ __align__(16) short pbL[32 * PSTR];
    __shared__ __align__(16) short attL[32 * 40];   // bf16 A-layout for mix
    __shared__ __align__(16) short msgT[128 * 40];  // bf16 B^T layout for mix
    __shared__ __align__(16) short hidL[32 * 136];
    __shared__ __align__(16) float b1L[PSTR], w2L[PSTR];

    const int b = blockIdx.x;
    const int tid = threadIdx.x;
    const int wave = tid >> 6, lane = tid & 63;
    const int quad = lane >> 4, lrow = lane & 15;
    const int nr = nrec_g[b];

    // ---- prefetch P1 tile-0 weights (depends on nothing; hides under P0) ----
    short8 wvA[9];
    {
        const short* bw = Wproj + (wave * 16 + lrow) * KHW + quad * 8;
#pragma unroll
        for (int kk = 0; kk < 9; ++kk) wvA[kk] = *(const short8*)(bw + kk * 32);
    }

    // ---- P0: load h0 bf16, zero pads, stage padded b1/w2 ----
    for (int idx = tid; idx < 32 * 64; idx += 1024) {         // nodes (float4)
        int w = idx >> 6, c4 = idx & 63;
        floatx4 v = *(const floatx4*)(nodes + ((size_t)(b * 32 + w)) * FEAT + c4 * 4);
        short4v s; s[0] = f2bf(v[0]); s[1] = f2bf(v[1]); s[2] = f2bf(v[2]); s[3] = f2bf(v[3]);
        *(short4v*)(bufA + w * KA_S + 128 + c4 * 4) = s;
    }
    for (int idx = tid; idx < 32 * POSD; idx += 1024) {       // pos
        int w = idx / POSD, c = idx % POSD;
        bufA[w * KA_S + 128 + FEAT + c] = f2bf(pos[((size_t)(b * 32 + w)) * POSD + c]);
    }
    for (int idx = tid; idx < 32 * 34; idx += 1024) {         // col pads 390..423
        int w = idx / 34, c = idx % 34;
        bufA[w * KA_S + 390 + c] = 0;
        bufB[w * KA_S + 390 + c] = 0;
    }
    for (int idx = tid; idx < 32 * (PSTR - D); idx += 1024) { // pa/pb pads 262..319
        int w = idx / (PSTR - D), c = idx % (PSTR - D);
        paL[w * PSTR + D + c] = 0;
        pbL[w * PSTR + D + c] = 0;
    }
    for (int d = tid; d < PSTR; d += 1024) {
        b1L[d] = (d < D) ? b1g[d] : 0.f;
        w2L[d] = (d < D) ? w2g[d] : 0.f;
    }
    __syncthreads();

    // ---- P1: combined GEMM over h0 (tiles 0..32 proj, 33..40 round-0 msg) ----
    // Software-pipelined across the wave's 2-3 tiles; weights batch-staged.
    {
        auto store_proj = [&](int s, floatx4 acc0, floatx4 acc1) {
            int col = s * 16 + lrow;
#pragma unroll
            for (int rr = 0; rr < 4; ++rr) {
                int r0 = quad * 4 + rr;
                if (col < D) {
                    paL[r0 * PSTR + col] = f2bf(acc0[rr]);
                    paL[(r0 + 16) * PSTR + col] = f2bf(acc1[rr]);
                } else if (col < 2 * D) {
                    pbL[r0 * PSTR + (col - D)] = f2bf(acc0[rr]);
                    pbL[(r0 + 16) * PSTR + (col - D)] = f2bf(acc1[rr]);
                }
            }
        };
        auto store_msg = [&](int s, floatx4 acc0, floatx4 acc1) {
            int col = (s - 33) * 16 + lrow;
            float bias = msg_bg[col];
#pragma unroll
            for (int rr = 0; rr < 4; ++rr) {
                msgT[col * 40 + quad * 4 + rr] = f2bf(acc0[rr] + bias);
                msgT[col * 40 + 16 + quad * 4 + rr] = f2bf(acc1[rr] + bias);
            }
        };
        const short* ap = bufA + lrow * KA_S + 128 + quad * 8;

        // stage t1 while computing t0 (with preloaded wvA)
        const int t1 = wave + 16;                    // 16..31: always proj
        short8 wvB[9];
        {
            const short* bw = Wproj + (t1 * 16 + lrow) * KHW + quad * 8;
#pragma unroll
            for (int kk = 0; kk < 9; ++kk) wvB[kk] = *(const short8*)(bw + kk * 32);
        }
        floatx4 a0 = {}, a1 = {};
#pragma unroll
        for (int kk = 0; kk < 9; ++kk) {
            short8 x0 = *(const short8*)(ap + kk * 32);
            short8 x1 = *(const short8*)(ap + 16 * KA_S + kk * 32);
            a0 = MFMA(x0, wvA[kk], a0, 0, 0, 0);
            a1 = MFMA(x1, wvA[kk], a1, 0, 0, 0);
        }

        // stage t2 into wvA while computing t1
        const int t2 = wave + 32;                    // 32..40 for waves 0..8
        const bool has2 = t2 < 41;
        if (has2) {
            const short* bw = (t2 < 33)
                ? Wproj + (t2 * 16 + lrow) * KHW + quad * 8
                : Wmsg + ((t2 - 33) * 16 + lrow) * KHW + quad * 8;
#pragma unroll
            for (int kk = 0; kk < 9; ++kk) wvA[kk] = *(const short8*)(bw + kk * 32);
        }
        store_proj(wave, a0, a1);

        floatx4 b0 = {}, b1 = {};
#pragma unroll
        for (int kk = 0; kk < 9; ++kk) {
            short8 x0 = *(const short8*)(ap + kk * 32);
            short8 x1 = *(const short8*)(ap + 16 * KA_S + kk * 32);
            b0 = MFMA(x0, wvB[kk], b0, 0, 0, 0);
            b1 = MFMA(x1, wvB[kk], b1, 0, 0, 0);
        }
        store_proj(t1, b0, b1);

        if (has2) {
            floatx4 c0 = {}, c1 = {};
#pragma unroll
            for (int kk = 0; kk < 9; ++kk) {
                short8 x0 = *(const short8*)(ap + kk * 32);
                short8 x1 = *(const short8*)(ap + 16 * KA_S + kk * 32);
                c0 = MFMA(x0, wvA[kk], c0, 0, 0, 0);
                c1 = MFMA(x1, wvA[kk], c1, 0, 0, 0);
            }
            if (t2 < 33) store_proj(t2, c0, c1);
            else         store_msg(t2, c0, c1);
        }
    }
    __syncthreads();

    // ---- P2: attention — 64 groups of 16 lanes, each does 16 j's ----
    {
        const int grp = tid >> 4;          // 0..63
        const int i   = grp >> 1;          // receiver node
        const int jh  = (grp & 1) * 16;    // j-half base
        const int c16 = tid & 15;
        const float b2v = b2g[0];
        float pav[5][4], b1v[5][4], w2v[5][4];
#pragma unroll
        for (int k = 0; k < 5; ++k) {
            int dbase = c16 * 4 + 64 * k;
            short4v p = *(const short4v*)(paL + i * PSTR + dbase);
            floatx4 bb = *(const floatx4*)(b1L + dbase);
            floatx4 ww = *(const floatx4*)(w2L + dbase);
#pragma unroll
            for (int e = 0; e < 4; ++e) {
                pav[k][e] = bf2f(p[e]); b1v[k][e] = bb[e]; w2v[k][e] = ww[e];
            }
        }
        // c0 = invalid-pair logit
        float p0 = 0.f;
#pragma unroll
        for (int k = 0; k < 5; ++k)
#pragma unroll
            for (int e = 0; e < 4; ++e)
                p0 += fmaxf(b1v[k][e], 0.f) * w2v[k][e];
        p0 += __shfl_down(p0, 8, 16); p0 += __shfl_down(p0, 4, 16);
        p0 += __shfl_down(p0, 2, 16); p0 += __shfl_down(p0, 1, 16);
        float c0 = sigf(p0 + b2v);
        const bool vi = i < nr;
        for (int jj = 0; jj < 16; ++jj) {
            int j = jh + jj;
            float a;
            if (j < nr && vi) {
                const short* pb = pbL + j * PSTR + c16 * 4;
                float s = 0.f;
#pragma unroll
                for (int k = 0; k < 5; ++k) {
                    short4v q = *(const short4v*)(pb + 64 * k);
#pragma unroll
                    for (int e = 0; e < 4; ++e) {
                        float v = pav[k][e] + bf2f(q[e]) + b1v[k][e];
                        s += fmaxf(v, 0.f) * w2v[k][e];
                    }
                }
                s += __shfl_down(s, 8, 16); s += __shfl_down(s, 4, 16);
                s += __shfl_down(s, 2, 16); s += __shfl_down(s, 1, 16);
                a = sigf(s + b2v);
            } else {
                a = c0;
            }
            if (c16 == 0) {
                att_out[((size_t)(b * 32 + i)) * 32 + j] = a;
                attL[i * 40 + j] = f2bf((j < nr) ? a : 0.f);
            }
        }
    }
    __syncthreads();

    // ---- two message-passing rounds ----
    for (int rnd = 0; rnd < 2; ++rnd) {
        short* src = rnd ? bufB : bufA;
        short* dst = rnd ? bufA : bufB;

        // msg = h @ Wmsg^T + msg_b -> msgT bf16 (round 0 done in P1)
        if (rnd) {
            int s = wave >> 1, mi = wave & 1;
            const short* bw = Wmsg + (s * 16 + lrow) * KHW + quad * 8;
            short8 wm[9];
#pragma unroll
            for (int kk = 0; kk < 9; ++kk) wm[kk] = *(const short8*)(bw + kk * 32);
            floatx4 acc = {};
            const short* ap = src + (mi * 16 + lrow) * KA_S + 128 + quad * 8;
#pragma unroll
            for (int kk = 0; kk < 9; ++kk) {
                short8 a0 = *(const short8*)(ap + kk * 32);
                acc = MFMA(a0, wm[kk], acc, 0, 0, 0);
            }
            int col = s * 16 + lrow;
            float bias = msg_bg[col];
#pragma unroll
            for (int rr = 0; rr < 4; ++rr)
                msgT[col * 40 + mi * 16 + quad * 4 + rr] = f2bf(acc[rr] + bias);
            __syncthreads();
        }

        // mix via MFMA: mv = attL(32x32) @ msg -> bf16 src cols 0..127
        {
            int mi = wave & 1, ng = wave >> 1;     // ng 0..7: 16 cols each
            short8 afrag = *(const short8*)(attL + (mi * 16 + lrow) * 40 + quad * 8);
            floatx4 acc = {};
            short8 bf0 = *(const short8*)(msgT + (ng * 16 + lrow) * 40 + quad * 8);
            acc = MFMA(afrag, bf0, acc, 0, 0, 0);
#pragma unroll
            for (int rr = 0; rr < 4; ++rr) {
                int m = mi * 16 + quad * 4 + rr;
                src[m * KA_S + ng * 16 + lrow] = f2bf(acc[rr]);
            }
        }
        __syncthreads();

        // GRU: fused [gx|gh] GEMM + elementwise, writes dst h-cols.
        // Full units: 17 d-tiles over 16 waves (wave 0 takes tile 16 too).
        // Weights staged once per tile, consumed by BOTH row-halves; z then h
        // streams rotate into the same regs while the current chain's MFMAs run
        // -> 13 loads continuously in flight.
        for (int s = wave; s < 17; s += 16) {
            const short* ap0 = src + lrow * KA_S + quad * 8;
            const short* ap1 = ap0 + 16 * KA_S;
            const short* bpr = Wrz + (s * 16 + lrow) * KFULL + quad * 8;
            const short* bpz = bpr + 272 * KFULL;
            const short* bpx = Wxn + (s * 16 + lrow) * 128 + quad * 8;
            const short* bph = Whn + (s * 16 + lrow) * KHW + quad * 8;

            short8 wr[13];
#pragma unroll
            for (int kk = 0; kk < 13; ++kk) wr[kk] = *(const short8*)(bpr + kk * 32);

            floatx4 aR0 = {}, aR1 = {}, aZ0 = {}, aZ1 = {};
            floatx4 aN0 = {}, aN1 = {}, aH0 = {}, aH1 = {};
#pragma unroll
            for (int kk = 0; kk < 13; ++kk) {           // r (+x inline) ; stage z
                short8 x0 = *(const short8*)(ap0 + kk * 32);
                short8 x1 = *(const short8*)(ap1 + kk * 32);
                aR0 = MFMA(x0, wr[kk], aR0, 0, 0, 0);
                aR1 = MFMA(x1, wr[kk], aR1, 0, 0, 0);
                if (kk < 4) {
                    short8 bx = *(const short8*)(bpx + kk * 32);
                    aN0 = MFMA(x0, bx, aN0, 0, 0, 0);
                    aN1 = MFMA(x1, bx, aN1, 0, 0, 0);
                }
                wr[kk] = *(const short8*)(bpz + kk * 32);
            }
#pragma unroll
            for (int kk = 0; kk < 13; ++kk) {           // z chain ; stage h
                short8 x0 = *(const short8*)(ap0 + kk * 32);
                short8 x1 = *(const short8*)(ap1 + kk * 32);
                aZ0 = MFMA(x0, wr[kk], aZ0, 0, 0, 0);
                aZ1 = MFMA(x1, wr[kk], aZ1, 0, 0, 0);
                if (kk < 9) wr[kk] = *(const short8*)(bph + kk * 32);
            }
#pragma unroll
            for (int kk = 0; kk < 9; ++kk) {            // h chain
                short8 x0 = *(const short8*)(ap0 + (4 + kk) * 32);
                short8 x1 = *(const short8*)(ap1 + (4 + kk) * 32);
                aH0 = MFMA(x0, wr[kk], aH0, 0, 0, 0);
                aH1 = MFMA(x1, wr[kk], aH1, 0, 0, 0);
            }

            int d = s * 16 + lrow;
            if (d < D) {
                float bgr = gb[d], bgz = gb[272 + d];
                float bxv = gb[544 + d], bhv = gb[816 + d];
#pragma unroll
                for (int i = 0; i < 2; ++i) {
                    floatx4 vR = i ? aR1 : aR0, vZ = i ? aZ1 : aZ0;
                    floatx4 vN = i ? aN1 : aN0, vH = i ? aH1 : aH0;
#pragma unroll
                    for (int rr = 0; rr < 4; ++rr) {
                        int m = i * 16 + quad * 4 + rr;
                        float rg = sigf(vR[rr] + bgr);
                        float zg = sigf(vZ[rr] + bgz);
                        float cg = tanh_fast(vN[rr] + bxv + rg * (vH[rr] + bhv));
                        float hold = bf2f(src[m * KA_S + 128 + d]);
                        float hv = (1.f - zg) * cg + zg * hold;
                        if (m >= nr) hv = 0.f;
                        dst[m * KA_S + 128 + d] = f2bf(hv);
                    }
                }
            }
        }
        __syncthreads();
    }

    // ---- readout: hid = relu(h2 @ Wro^T + ro_b1), h2 in bufA ----
    {
        int s = wave >> 1, mi = wave & 1;
        const short* bw = Wro + (s * 16 + lrow) * KHW + quad * 8;
        short8 wv[9];
#pragma unroll
        for (int kk = 0; kk < 9; ++kk) wv[kk] = *(const short8*)(bw + kk * 32);
        floatx4 acc = {};
        const short* ap = bufA + (mi * 16 + lrow) * KA_S + 128 + quad * 8;
#pragma unroll
        for (int kk = 0; kk < 9; ++kk) {
            short8 a0 = *(const short8*)(ap + kk * 32);
            acc = MFMA(a0, wv[kk], acc, 0, 0, 0);
        }
        int col = s * 16 + lrow;
        float bias = ro_b1g[col];
#pragma unroll
        for (int rr = 0; rr < 4; ++rr)
            hidL[(mi * 16 + quad * 4 + rr) * 136 + col] = f2bf(fmaxf(acc[rr] + bias, 0.f));
    }
    __syncthreads();

    // ---- final: pred = hid @ ro_w2^T + ro_b2 (waves 0,1) ----
    if (wave < 2) {
        const short* bw = Wro2 + lrow * 128 + quad * 8;
        short8 wv[4];
#pragma unroll
        for (int kk = 0; kk < 4; ++kk) wv[kk] = *(const short8*)(bw + kk * 32);
        floatx4 acc = {};
        const short* ap = hidL + (wave * 16 + lrow) * 136 + quad * 8;
#pragma unroll
        for (int kk = 0; kk < 4; ++kk) {
            short8 a0 = *(const short8*)(ap + kk * 32);
            acc = MFMA(a0, wv[kk], acc, 0, 0, 0);
        }
        int q = lrow;
        if (q < NCLS) {
            float bias = ro_b2g[q];
#pragma unroll
            for (int rr = 0; rr < 4; ++rr) {
                int m = wave * 16 + quad * 4 + rr;
                float v = acc[rr] + bias;
                if (m >= nr) v = 0.f;
                pred[((size_t)(b * 32 + m)) * NCLS + q] = v;
            }
        }
    }
}

// ---------------------------------------------------------------------------
extern "C" void kernel_launch(void* const* d_in, const int* in_sizes, int n_in,
                              void* d_out, int out_size, void* d_ws, size_t ws_size,
                              hipStream_t stream)
{
    const float* nodes = (const float*)d_in[0];
    const float* pos   = (const float*)d_in[1];
    const int*   nrec  = (const int*)d_in[2];
    const float* w1    = (const float*)d_in[3];
    const float* b1    = (const float*)d_in[4];
    const float* w2    = (const float*)d_in[5];
    const float* b2    = (const float*)d_in[6];
    const float* msg_w = (const float*)d_in[7];
    const float* msg_b = (const float*)d_in[8];
    const float* w_ih  = (const float*)d_in[9];
    const float* w_hh  = (const float*)d_in[10];
    const float* b_ih  = (const float*)d_in[11];
    const float* b_hh  = (const float*)d_in[12];
    const float* ro_w1 = (const float*)d_in[13];
    const float* ro_b1 = (const float*)d_in[14];
    const float* ro_w2 = (const float*)d_in[15];
    const float* ro_b2 = (const float*)d_in[16];
    float* ws   = (float*)d_ws;
    float* pred = (float*)d_out;
    float* attout = pred + (size_t)N_G * M_N * NCLS;

    prep_kernel<<<256, 256, 0, stream>>>(w1, msg_w, w_ih, w_hh, ro_w1, ro_w2,
                                         b_ih, b_hh, ws);
    fused_kernel<<<N_G, 1024, 0, stream>>>(nodes, pos, nrec, b1, w2, b2, msg_b,
                                           ro_b1, ro_b2, ws, attout, pred);
}

// Round 4
// 153.409 us; speedup vs baseline: 1.4052x; 1.4052x over previous
//
#include <hip/hip_runtime.h>
#include <math.h>

#define N_G   64
#define M_N   32
#define FEAT  256
#define POSD  6
#define D     262
#define MSG   128
#define NCLS  7

#define KA_S  424       // LDS buf row stride (shorts): [mv 128 | h 262 | pad]
#define KHW   288       // weight K window over h (262 -> 288)
#define KFULL 416       // full concat K
#define PSTR  320       // paL/pbL row stride (shorts), covers c16*4+64k up to 316

// packed weight sizes (shorts)
#define S_PROJ (528*288)
#define S_MSG  (128*288)
#define S_RZ   (544*416)
#define S_XN   (272*128)
#define S_HN   (272*288)
#define S_RO   (128*288)
#define S_RO2  (16*128)

// workspace float offsets
#define O_WPROJ 0u
#define O_WMSG  76032u
#define O_WRZ   94464u
#define O_WXN   207616u
#define O_WHN   225024u
#define O_WRO   264192u
#define O_WRO2  282624u
#define O_GB    283648u   // 1088 fp32 gate biases [br|bz|bxn|bhn] x 272

typedef __attribute__((ext_vector_type(8))) short short8;
typedef __attribute__((ext_vector_type(4))) short short4v;
typedef __attribute__((ext_vector_type(4))) float floatx4;

#define MFMA __builtin_amdgcn_mfma_f32_16x16x32_bf16

__device__ __forceinline__ short f2bf(float f) {
    union { float f; unsigned u; } v; v.f = f;
    unsigned r = v.u + 0x7FFF + ((v.u >> 16) & 1);   // RNE
    return (short)(r >> 16);
}
__device__ __forceinline__ float bf2f(short s) {
    union { float f; unsigned u; } v;
    v.u = ((unsigned)(unsigned short)s) << 16;
    return v.f;
}
// fast sigmoid/tanh: v_exp_f32 + v_rcp_f32 (~1e-6 rel err, vs bf16-path 5e-3)
__device__ __forceinline__ float sigf(float x) {
    return __builtin_amdgcn_rcpf(1.f + __expf(-x));
}
__device__ __forceinline__ float tanh_fast(float x) {
    float e = __expf(-2.f * fabsf(x));
    float t = (1.f - e) * __builtin_amdgcn_rcpf(1.f + e);
    return copysignf(t, x);
}

// ---------------------------------------------------------------------------
// prep: pack all weights bf16 [n][k] (B^T) with padded/zeroed windows + biases
// ---------------------------------------------------------------------------
__global__ void prep_kernel(const float* __restrict__ w1, const float* __restrict__ msg_w,
                            const float* __restrict__ w_ih, const float* __restrict__ w_hh,
                            const float* __restrict__ ro_w1, const float* __restrict__ ro_w2,
                            const float* __restrict__ b_ih, const float* __restrict__ b_hh,
                            float* __restrict__ ws)
{
    short* wproj = (short*)(ws + O_WPROJ);
    short* wmsg  = (short*)(ws + O_WMSG);
    short* wrz   = (short*)(ws + O_WRZ);
    short* wxn   = (short*)(ws + O_WXN);
    short* whn   = (short*)(ws + O_WHN);
    short* wro   = (short*)(ws + O_WRO);
    short* wro2  = (short*)(ws + O_WRO2);
    float* gb    = ws + O_GB;
    const int TOT_S = S_PROJ + S_MSG + S_RZ + S_XN + S_HN + S_RO + S_RO2;
    const int TOTAL = TOT_S + 1088;
    for (int i = blockIdx.x * blockDim.x + threadIdx.x; i < TOTAL;
         i += gridDim.x * blockDim.x) {
        int idx = i;
        if (idx < S_PROJ) {                       // [528][288]
            int n = idx / 288, k = idx % 288;
            float v = 0.f;
            if (k < D && n < 524)
                v = (n < D) ? w1[n * 524 + k] : w1[(n - D) * 524 + D + k];
            wproj[idx] = f2bf(v);
            continue;
        }
        idx -= S_PROJ;
        if (idx < S_MSG) {                        // [128][288]
            int n = idx / 288, k = idx % 288;
            wmsg[idx] = f2bf(k < D ? msg_w[n * D + k] : 0.f);
            continue;
        }
        idx -= S_MSG;
        if (idx < S_RZ) {                         // [544][416]: rows 0..271 r, 272..543 z
            int g = idx / 416, k = idx % 416;
            int gi = (g < 272) ? 0 : 1;
            int d = g - gi * 272;
            float v = 0.f;
            if (d < D) {
                int row = gi * D + d;
                if (k < 128)            v = w_ih[row * MSG + k];
                else if (k < 128 + D)   v = w_hh[row * D + (k - 128)];
            }
            wrz[idx] = f2bf(v);
            continue;
        }
        idx -= S_RZ;
        if (idx < S_XN) {                         // [272][128]
            int d = idx / 128, k = idx % 128;
            wxn[idx] = f2bf(d < D ? w_ih[(2 * D + d) * MSG + k] : 0.f);
            continue;
        }
        idx -= S_XN;
        if (idx < S_HN) {                         // [272][288]
            int d = idx / 288, k = idx % 288;
            whn[idx] = f2bf((d < D && k < D) ? w_hh[(2 * D + d) * D + k] : 0.f);
            continue;
        }
        idx -= S_HN;
        if (idx < S_RO) {                         // [128][288]
            int n = idx / 288, k = idx % 288;
            wro[idx] = f2bf(k < D ? ro_w1[n * D + k] : 0.f);
            continue;
        }
        idx -= S_RO;
        if (idx < S_RO2) {                        // [16][128]
            int n = idx / 128, k = idx % 128;
            wro2[idx] = f2bf(n < NCLS ? ro_w2[n * MSG + k] : 0.f);
            continue;
        }
        idx -= S_RO2;
        {                                          // gate biases [4][272]
            int seg = idx / 272, d = idx % 272;
            float v = 0.f;
            if (d < D) {
                if (seg == 0)      v = b_ih[d] + b_hh[d];
                else if (seg == 1) v = b_ih[D + d] + b_hh[D + d];
                else if (seg == 2) v = b_ih[2 * D + d];
                else               v = b_hh[2 * D + d];
            }
            gb[idx] = v;
        }
    }
}

// ---------------------------------------------------------------------------
// fused: one block per graph; full forward in LDS.
// Round-4: 512 threads (8 waves = 2/SIMD block minimum -> VGPR ceiling 256;
// 1024-thr blocks have a HARD 128 ceiling that made R2/R3's staging spill).
// Latency attack, two prongs:
//  (1) explicit register staging / rotation of every weight stream so 9-13
//      loads are in flight per K-chain instead of ~1 (loop-carried vmcnt(0));
//  (2) L2 priming: 10 fire-and-forget 128B-strided touches per wave cover the
//      GRU weight region (679 KB) at kernel start; by GRU time lines are L2-hot
//      (~200cy) instead of L3/HBM-cold (~600-900cy).
// ---------------------------------------------------------------------------
__global__ __launch_bounds__(512, 2) void fused_kernel(
    const float* __restrict__ nodes, const float* __restrict__ pos,
    const int* __restrict__ nrec_g,
    const float* __restrict__ b1g, const float* __restrict__ w2g,
    const float* __restrict__ b2g, const float* __restrict__ msg_bg,
    const float* __restrict__ ro_b1g, const float* __restrict__ ro_b2g,
    const float* __restrict__ ws,
    float* __restrict__ att_out, float* __restrict__ pred)
{
    const short* Wproj = (const short*)(ws + O_WPROJ);
    const short* Wmsg  = (const short*)(ws + O_WMSG);
    const short* Wrz   = (const short*)(ws + O_WRZ);
    const short* Wxn   = (const short*)(ws + O_WXN);
    const short* Whn   = (const short*)(ws + O_WHN);
    const short* Wro   = (const short*)(ws + O_WRO);
    const short* Wro2  = (const short*)(ws + O_WRO2);
    const float* gb    = ws + O_GB;

    __shared__ __align__(16) short bufA[32 * KA_S];
    __shared__ __align__(16) short bufB[32 * KA_S];
    __shared__ __align__(16) short paL[32 * PSTR];
    __shared__ __align__(16) short pbL[32 * PSTR];
    __shared__ __align__(16) short attL[32 * 40];   // bf16 A-layout for mix
    __shared__ __align__(16) short msgT[128 * 40];  // bf16 B^T layout for mix
    __shared__ __align__(16) short hidL[32 * 136];
    __shared__ __align__(16) float b1L[PSTR], w2L[PSTR];

    const int b = blockIdx.x;
    const int tid = threadIdx.x;
    const int wave = tid >> 6, lane = tid & 63;
    const int quad = lane >> 4, lrow = lane & 15;

    // ---- L2 priming: touch Wrz/Wxn/Whn (contiguous 679 KB) early ----
    // 10 insts x 8 waves x 64 lanes x 128B line = 640 KB coverage. Values are
    // discarded; the asm keep-alive before the first barrier prevents DCE.
    floatx4 prm[10];
    {
        const floatx4* pb = (const floatx4*)(ws + O_WRZ);
        const int base = wave * 64 + lane;
#pragma unroll
        for (int p = 0; p < 10; ++p)
            prm[p] = pb[(p * 512 + base) * 8];      // 8 floatx4 = 128 B stride
    }
    // ---- prefetch P1 tile-'wave' weights (hides under P0) ----
    short8 wvA[9];
    {
        const short* bw = Wproj + (wave * 16 + lrow) * KHW + quad * 8;
#pragma unroll
        for (int kk = 0; kk < 9; ++kk) wvA[kk] = *(const short8*)(bw + kk * 32);
    }

    const int nr = nrec_g[b];

    // ---- P0: load h0 bf16, zero pads, stage padded b1/w2 ----
    for (int idx = tid; idx < 32 * 64; idx += 512) {          // nodes (float4)
        int w = idx >> 6, c4 = idx & 63;
        floatx4 v = *(const floatx4*)(nodes + ((size_t)(b * 32 + w)) * FEAT + c4 * 4);
        short4v s; s[0] = f2bf(v[0]); s[1] = f2bf(v[1]); s[2] = f2bf(v[2]); s[3] = f2bf(v[3]);
        *(short4v*)(bufA + w * KA_S + 128 + c4 * 4) = s;
    }
    for (int idx = tid; idx < 32 * POSD; idx += 512) {        // pos
        int w = idx / POSD, c = idx % POSD;
        bufA[w * KA_S + 128 + FEAT + c] = f2bf(pos[((size_t)(b * 32 + w)) * POSD + c]);
    }
    for (int idx = tid; idx < 32 * 34; idx += 512) {          // col pads 390..423
        int w = idx / 34, c = idx % 34;
        bufA[w * KA_S + 390 + c] = 0;
        bufB[w * KA_S + 390 + c] = 0;
    }
    for (int idx = tid; idx < 32 * (PSTR - D); idx += 512) {  // pa/pb pads 262..319
        int w = idx / (PSTR - D), c = idx % (PSTR - D);
        paL[w * PSTR + D + c] = 0;
        pbL[w * PSTR + D + c] = 0;
    }
    for (int d = tid; d < PSTR; d += 512) {
        b1L[d] = (d < D) ? b1g[d] : 0.f;
        w2L[d] = (d < D) ? w2g[d] : 0.f;
    }
    // keep priming loads alive (and let their latency overlap P0's work)
#pragma unroll
    for (int p = 0; p < 10; ++p) asm volatile("" :: "v"(prm[p]));
    __syncthreads();

    // ---- P1: combined GEMM over h0 (tiles 0..32 proj, 33..40 round-0 msg) ----
    // 5-6 tiles per wave, double-buffered weight staging (wvA/wvB, 9 in flight).
    {
        auto store_proj = [&](int s, floatx4 acc0, floatx4 acc1) {
            int col = s * 16 + lrow;
#pragma unroll
            for (int rr = 0; rr < 4; ++rr) {
                int r0 = quad * 4 + rr;
                if (col < D) {
                    paL[r0 * PSTR + col] = f2bf(acc0[rr]);
                    paL[(r0 + 16) * PSTR + col] = f2bf(acc1[rr]);
                } else if (col < 2 * D) {
                    pbL[r0 * PSTR + (col - D)] = f2bf(acc0[rr]);
                    pbL[(r0 + 16) * PSTR + (col - D)] = f2bf(acc1[rr]);
                }
            }
        };
        auto store_msg = [&](int s, floatx4 acc0, floatx4 acc1) {
            int col = (s - 33) * 16 + lrow;
            float bias = msg_bg[col];
#pragma unroll
            for (int rr = 0; rr < 4; ++rr) {
                msgT[col * 40 + quad * 4 + rr] = f2bf(acc0[rr] + bias);
                msgT[col * 40 + 16 + quad * 4 + rr] = f2bf(acc1[rr] + bias);
            }
        };
        const short* ap = bufA + lrow * KA_S + 128 + quad * 8;
        short8 wvB[9];

#define P1_LOAD(DST, TT) do { \
            const short* bw_ = ((TT) < 33) \
                ? Wproj + ((TT) * 16 + lrow) * KHW + quad * 8 \
                : Wmsg + (((TT) - 33) * 16 + lrow) * KHW + quad * 8; \
            _Pragma("unroll") \
            for (int kk = 0; kk < 9; ++kk) DST[kk] = *(const short8*)(bw_ + kk * 32); \
        } while (0)

#define P1_TILE(W, TT) do { \
            floatx4 acc0_ = {}, acc1_ = {}; \
            _Pragma("unroll") \
            for (int kk = 0; kk < 9; ++kk) { \
                short8 x0 = *(const short8*)(ap + kk * 32); \
                short8 x1 = *(const short8*)(ap + 16 * KA_S + kk * 32); \
                acc0_ = MFMA(x0, W[kk], acc0_, 0, 0, 0); \
                acc1_ = MFMA(x1, W[kk], acc1_, 0, 0, 0); \
            } \
            if ((TT) < 33) store_proj((TT), acc0_, acc1_); \
            else store_msg((TT), acc0_, acc1_); \
        } while (0)

        int t = wave;                       // 0..7
        P1_LOAD(wvB, t + 8);                // stage next while computing current
        P1_TILE(wvA, t);
        t += 8;                             // 8..15
        P1_LOAD(wvA, t + 8);
        P1_TILE(wvB, t);
        t += 8;                             // 16..23
        P1_LOAD(wvB, t + 8);
        P1_TILE(wvA, t);
        t += 8;                             // 24..31
        P1_LOAD(wvA, t + 8);                // 32..39: always valid
        P1_TILE(wvB, t);
        t += 8;                             // 32..39
        if (t + 8 < 41) P1_LOAD(wvB, t + 8);  // only wave 0 stages tile 40
        P1_TILE(wvA, t);
        t += 8;                             // 40 for wave 0
        if (t < 41) P1_TILE(wvB, t);
#undef P1_LOAD
#undef P1_TILE
    }
    __syncthreads();

    // ---- P2: attention — 32 groups of 16 lanes, 32 j's each ----
    {
        const int grp = tid >> 4;          // i = grp (0..31)
        const int c16 = tid & 15;
        const float b2v = b2g[0];
        float pav[5][4], b1v[5][4], w2v[5][4];
#pragma unroll
        for (int k = 0; k < 5; ++k) {
            int dbase = c16 * 4 + 64 * k;
            short4v p = *(const short4v*)(paL + grp * PSTR + dbase);
            floatx4 bb = *(const floatx4*)(b1L + dbase);
            floatx4 ww = *(const floatx4*)(w2L + dbase);
#pragma unroll
            for (int e = 0; e < 4; ++e) {
                pav[k][e] = bf2f(p[e]); b1v[k][e] = bb[e]; w2v[k][e] = ww[e];
            }
        }
        // c0 = invalid-pair logit
        float p0 = 0.f;
#pragma unroll
        for (int k = 0; k < 5; ++k)
#pragma unroll
            for (int e = 0; e < 4; ++e)
                p0 += fmaxf(b1v[k][e], 0.f) * w2v[k][e];
        p0 += __shfl_down(p0, 8, 16); p0 += __shfl_down(p0, 4, 16);
        p0 += __shfl_down(p0, 2, 16); p0 += __shfl_down(p0, 1, 16);
        float c0 = sigf(p0 + b2v);
        const bool vi = grp < nr;
        for (int j = 0; j < 32; ++j) {
            float a;
            if (j < nr && vi) {
                const short* pb = pbL + j * PSTR + c16 * 4;
                float s = 0.f;
#pragma unroll
                for (int k = 0; k < 5; ++k) {
                    short4v q = *(const short4v*)(pb + 64 * k);
#pragma unroll
                    for (int e = 0; e < 4; ++e) {
                        float v = pav[k][e] + bf2f(q[e]) + b1v[k][e];
                        s += fmaxf(v, 0.f) * w2v[k][e];
                    }
                }
                s += __shfl_down(s, 8, 16); s += __shfl_down(s, 4, 16);
                s += __shfl_down(s, 2, 16); s += __shfl_down(s, 1, 16);
                a = sigf(s + b2v);
            } else {
                a = c0;
            }
            if (c16 == 0) {
                att_out[((size_t)(b * 32 + grp)) * 32 + j] = a;
                attL[grp * 40 + j] = f2bf((j < nr) ? a : 0.f);
            }
        }
    }
    __syncthreads();

    // ---- two message-passing rounds ----
    for (int rnd = 0; rnd < 2; ++rnd) {
        short* src = rnd ? bufB : bufA;
        short* dst = rnd ? bufA : bufB;

        // msg = h @ Wmsg^T + msg_b -> msgT bf16 (round 0 done in P1)
        if (rnd) {
            int s = wave;
            const short* bw = Wmsg + (s * 16 + lrow) * KHW + quad * 8;
            short8 wm[9];
#pragma unroll
            for (int kk = 0; kk < 9; ++kk) wm[kk] = *(const short8*)(bw + kk * 32);
            floatx4 acc0 = {}, acc1 = {};
            const short* ap = src + lrow * KA_S + 128 + quad * 8;
#pragma unroll
            for (int kk = 0; kk < 9; ++kk) {
                short8 x0 = *(const short8*)(ap + kk * 32);
                short8 x1 = *(const short8*)(ap + 16 * KA_S + kk * 32);
                acc0 = MFMA(x0, wm[kk], acc0, 0, 0, 0);
                acc1 = MFMA(x1, wm[kk], acc1, 0, 0, 0);
            }
            int col = s * 16 + lrow;
            float bias = msg_bg[col];
#pragma unroll
            for (int rr = 0; rr < 4; ++rr) {
                msgT[col * 40 + quad * 4 + rr] = f2bf(acc0[rr] + bias);
                msgT[col * 40 + 16 + quad * 4 + rr] = f2bf(acc1[rr] + bias);
            }
            __syncthreads();
        }

        // mix via MFMA: mv = attL(32x32) @ msg -> bf16 src cols 0..127
        {
            int mi = wave & 1, ng = wave >> 1;
            short8 afrag = *(const short8*)(attL + (mi * 16 + lrow) * 40 + quad * 8);
            floatx4 acc0 = {}, acc1 = {};
            short8 bf0 = *(const short8*)(msgT + (ng * 32 + lrow) * 40 + quad * 8);
            short8 bf1 = *(const short8*)(msgT + (ng * 32 + 16 + lrow) * 40 + quad * 8);
            acc0 = MFMA(afrag, bf0, acc0, 0, 0, 0);
            acc1 = MFMA(afrag, bf1, acc1, 0, 0, 0);
#pragma unroll
            for (int rr = 0; rr < 4; ++rr) {
                int m = mi * 16 + quad * 4 + rr;
                src[m * KA_S + ng * 32 + lrow] = f2bf(acc0[rr]);
                src[m * KA_S + ng * 32 + 16 + lrow] = f2bf(acc1[rr]);
            }
        }
        __syncthreads();

        // GRU: fused [gx|gh] GEMM + elementwise, writes dst h-cols.
        // Full units (17 d-tiles over 8 waves); weight tile staged once and
        // consumed by both row-halves; z then h streams rotate into the same
        // registers while the current chain's MFMAs run (13 in flight).
        for (int s = wave; s < 17; s += 8) {
            const short* ap0 = src + lrow * KA_S + quad * 8;
            const short* ap1 = ap0 + 16 * KA_S;
            const short* bpr = Wrz + (s * 16 + lrow) * KFULL + quad * 8;
            const short* bpz = bpr + 272 * KFULL;
            const short* bpx = Wxn + (s * 16 + lrow) * 128 + quad * 8;
            const short* bph = Whn + (s * 16 + lrow) * KHW + quad * 8;

            short8 wr[13];
#pragma unroll
            for (int kk = 0; kk < 13; ++kk) wr[kk] = *(const short8*)(bpr + kk * 32);

            floatx4 aR0 = {}, aR1 = {}, aZ0 = {}, aZ1 = {};
            floatx4 aN0 = {}, aN1 = {}, aH0 = {}, aH1 = {};
#pragma unroll
            for (int kk = 0; kk < 13; ++kk) {           // r (+x inline); stage z
                short8 x0 = *(const short8*)(ap0 + kk * 32);
                short8 x1 = *(const short8*)(ap1 + kk * 32);
                aR0 = MFMA(x0, wr[kk], aR0, 0, 0, 0);
                aR1 = MFMA(x1, wr[kk], aR1, 0, 0, 0);
                if (kk < 4) {
                    short8 bx = *(const short8*)(bpx + kk * 32);
                    aN0 = MFMA(x0, bx, aN0, 0, 0, 0);
                    aN1 = MFMA(x1, bx, aN1, 0, 0, 0);
                }
                wr[kk] = *(const short8*)(bpz + kk * 32);
            }
#pragma unroll
            for (int kk = 0; kk < 13; ++kk) {           // z chain; stage h
                short8 x0 = *(const short8*)(ap0 + kk * 32);
                short8 x1 = *(const short8*)(ap1 + kk * 32);
                aZ0 = MFMA(x0, wr[kk], aZ0, 0, 0, 0);
                aZ1 = MFMA(x1, wr[kk], aZ1, 0, 0, 0);
                if (kk < 9) wr[kk] = *(const short8*)(bph + kk * 32);
            }
#pragma unroll
            for (int kk = 0; kk < 9; ++kk) {            // h chain
                short8 x0 = *(const short8*)(ap0 + (4 + kk) * 32);
                short8 x1 = *(const short8*)(ap1 + (4 + kk) * 32);
                aH0 = MFMA(x0, wr[kk], aH0, 0, 0, 0);
                aH1 = MFMA(x1, wr[kk], aH1, 0, 0, 0);
            }

            int d = s * 16 + lrow;
            if (d < D) {
                float bgr = gb[d], bgz = gb[272 + d];
                float bxv = gb[544 + d], bhv = gb[816 + d];
#pragma unroll
                for (int i = 0; i < 2; ++i) {
                    floatx4 vR = i ? aR1 : aR0, vZ = i ? aZ1 : aZ0;
                    floatx4 vN = i ? aN1 : aN0, vH = i ? aH1 : aH0;
#pragma unroll
                    for (int rr = 0; rr < 4; ++rr) {
                        int m = i * 16 + quad * 4 + rr;
                        float rg = sigf(vR[rr] + bgr);
                        float zg = sigf(vZ[rr] + bgz);
                        float cg = tanh_fast(vN[rr] + bxv + rg * (vH[rr] + bhv));
                        float hold = bf2f(src[m * KA_S + 128 + d]);
                        float hv = (1.f - zg) * cg + zg * hold;
                        if (m >= nr) hv = 0.f;
                        dst[m * KA_S + 128 + d] = f2bf(hv);
                    }
                }
            }
        }
        __syncthreads();
    }

    // ---- readout: hid = relu(h2 @ Wro^T + ro_b1), h2 in bufA ----
    {
        int s = wave;
        const short* bw = Wro + (s * 16 + lrow) * KHW + quad * 8;
        short8 wv[9];
#pragma unroll
        for (int kk = 0; kk < 9; ++kk) wv[kk] = *(const short8*)(bw + kk * 32);
        floatx4 acc0 = {}, acc1 = {};
        const short* ap = bufA + lrow * KA_S + 128 + quad * 8;
#pragma unroll
        for (int kk = 0; kk < 9; ++kk) {
            short8 x0 = *(const short8*)(ap + kk * 32);
            short8 x1 = *(const short8*)(ap + 16 * KA_S + kk * 32);
            acc0 = MFMA(x0, wv[kk], acc0, 0, 0, 0);
            acc1 = MFMA(x1, wv[kk], acc1, 0, 0, 0);
        }
        int col = s * 16 + lrow;
        float bias = ro_b1g[col];
#pragma unroll
        for (int rr = 0; rr < 4; ++rr) {
            hidL[(quad * 4 + rr) * 136 + col] = f2bf(fmaxf(acc0[rr] + bias, 0.f));
            hidL[(16 + quad * 4 + rr) * 136 + col] = f2bf(fmaxf(acc1[rr] + bias, 0.f));
        }
    }
    __syncthreads();

    // ---- final: pred = hid @ ro_w2^T + ro_b2 (wave 0 only) ----
    if (wave == 0) {
        const short* bw = Wro2 + lrow * 128 + quad * 8;
        short8 wv[4];
#pragma unroll
        for (int kk = 0; kk < 4; ++kk) wv[kk] = *(const short8*)(bw + kk * 32);
        floatx4 acc0 = {}, acc1 = {};
        const short* ap = hidL + lrow * 136 + quad * 8;
#pragma unroll
        for (int kk = 0; kk < 4; ++kk) {
            short8 x0 = *(const short8*)(ap + kk * 32);
            short8 x1 = *(const short8*)(ap + 16 * 136 + kk * 32);
            acc0 = MFMA(x0, wv[kk], acc0, 0, 0, 0);
            acc1 = MFMA(x1, wv[kk], acc1, 0, 0, 0);
        }
        int q = lrow;
        if (q < NCLS) {
            float bias = ro_b2g[q];
#pragma unroll
            for (int i = 0; i < 2; ++i) {
#pragma unroll
                for (int rr = 0; rr < 4; ++rr) {
                    int m = i * 16 + quad * 4 + rr;
                    float v = (i ? acc1[rr] : acc0[rr]) + bias;
                    if (m >= nr) v = 0.f;
                    pred[((size_t)(b * 32 + m)) * NCLS + q] = v;
                }
            }
        }
    }
}

// ---------------------------------------------------------------------------
extern "C" void kernel_launch(void* const* d_in, const int* in_sizes, int n_in,
                              void* d_out, int out_size, void* d_ws, size_t ws_size,
                              hipStream_t stream)
{
    const float* nodes = (const float*)d_in[0];
    const float* pos   = (const float*)d_in[1];
    const int*   nrec  = (const int*)d_in[2];
    const float* w1    = (const float*)d_in[3];
    const float* b1    = (const float*)d_in[4];
    const float* w2    = (const float*)d_in[5];
    const float* b2    = (const float*)d_in[6];
    const float* msg_w = (const float*)d_in[7];
    const float* msg_b = (const float*)d_in[8];
    const float* w_ih  = (const float*)d_in[9];
    const float* w_hh  = (const float*)d_in[10];
    const float* b_ih  = (const float*)d_in[11];
    const float* b_hh  = (const float*)d_in[12];
    const float* ro_w1 = (const float*)d_in[13];
    const float* ro_b1 = (const float*)d_in[14];
    const float* ro_w2 = (const float*)d_in[15];
    const float* ro_b2 = (const float*)d_in[16];
    float* ws   = (float*)d_ws;
    float* pred = (float*)d_out;
    float* attout = pred + (size_t)N_G * M_N * NCLS;

    prep_kernel<<<256, 256, 0, stream>>>(w1, msg_w, w_ih, w_hh, ro_w1, ro_w2,
                                         b_ih, b_hh, ws);
    fused_kernel<<<N_G, 512, 0, stream>>>(nodes, pos, nrec, b1, w2, b2, msg_b,
                                          ro_b1, ro_b2, ws, attout, pred);
}

// Round 5
// 149.966 us; speedup vs baseline: 1.4375x; 1.0230x over previous
//
#include <hip/hip_runtime.h>
#include <math.h>

#define N_G   64
#define M_N   32
#define FEAT  256
#define POSD  6
#define D     262
#define MSG   128
#define NCLS  7

#define KA_S  424       // LDS buf row stride (shorts): [mv 128 | h 262 | pad]
#define KHW   288       // weight K window over h (262 -> 288)
#define KFULL 416       // full concat K
#define PSTR  320       // paL/pbL row stride (shorts), covers c16*4+64k up to 316

// packed weight sizes (shorts)
#define S_PROJ (528*288)
#define S_MSG  (128*288)
#define S_RZ   (544*416)
#define S_XN   (272*128)
#define S_HN   (272*288)
#define S_RO   (128*288)
#define S_RO2  (16*128)

// workspace float offsets
#define O_WPROJ 0u
#define O_WMSG  76032u
#define O_WRZ   94464u
#define O_WXN   207616u
#define O_WHN   225024u
#define O_WRO   264192u
#define O_WRO2  282624u
#define O_GB    283648u   // 1088 fp32 gate biases [br|bz|bxn|bhn] x 272

typedef __attribute__((ext_vector_type(8))) short short8;
typedef __attribute__((ext_vector_type(4))) short short4v;
typedef __attribute__((ext_vector_type(4))) float floatx4;

#define MFMA __builtin_amdgcn_mfma_f32_16x16x32_bf16

__device__ __forceinline__ short f2bf(float f) {
    union { float f; unsigned u; } v; v.f = f;
    unsigned r = v.u + 0x7FFF + ((v.u >> 16) & 1);   // RNE
    return (short)(r >> 16);
}
__device__ __forceinline__ float bf2f(short s) {
    union { float f; unsigned u; } v;
    v.u = ((unsigned)(unsigned short)s) << 16;
    return v.f;
}
// fast sigmoid/tanh: v_exp_f32 + v_rcp_f32 (~1e-6 rel err, vs bf16-path 5e-3)
__device__ __forceinline__ float sigf(float x) {
    return __builtin_amdgcn_rcpf(1.f + __expf(-x));
}
__device__ __forceinline__ float tanh_fast(float x) {
    float e = __expf(-2.f * fabsf(x));
    float t = (1.f - e) * __builtin_amdgcn_rcpf(1.f + e);
    return copysignf(t, x);
}

// ---------------------------------------------------------------------------
// prep: pack all weights bf16 [n][k] (B^T) with padded/zeroed windows + biases.
// Round-5 rewrite: ROW-PER-WAVE. 1892 rows, one 64-lane wave each (473 blocks
// x 256 threads). No div/mod (segment resolved wave-uniformly from row id),
// coalesced k-loops of <=7 iterations, 7x the block-level parallelism of the
// old flat version (256 blocks, 9 loop-carried latency-exposed iterations).
// ---------------------------------------------------------------------------
__global__ __launch_bounds__(256) void prep_kernel(
    const float* __restrict__ w1, const float* __restrict__ msg_w,
    const float* __restrict__ w_ih, const float* __restrict__ w_hh,
    const float* __restrict__ ro_w1, const float* __restrict__ ro_w2,
    const float* __restrict__ b_ih, const float* __restrict__ b_hh,
    float* __restrict__ ws)
{
    short* wproj = (short*)(ws + O_WPROJ);
    short* wmsg  = (short*)(ws + O_WMSG);
    short* wrz   = (short*)(ws + O_WRZ);
    short* wxn   = (short*)(ws + O_WXN);
    short* whn   = (short*)(ws + O_WHN);
    short* wro   = (short*)(ws + O_WRO);
    short* wro2  = (short*)(ws + O_WRO2);
    float* gb    = ws + O_GB;

    int row = blockIdx.x * 4 + (threadIdx.x >> 6);
    const int lane = threadIdx.x & 63;
    if (row >= 1892) return;

    if (row < 528) {                              // wproj [528][288]
        const int n = row;
        short* out = wproj + n * 288;
        const float* src = (n < D) ? (w1 + n * 524) : (w1 + (n - D) * 524 + D);
        for (int k = lane; k < 288; k += 64) {
            float v = (k < D && n < 524) ? src[k] : 0.f;
            out[k] = f2bf(v);
        }
        return;
    }
    row -= 528;
    if (row < 128) {                              // wmsg [128][288]
        const int n = row;
        short* out = wmsg + n * 288;
        const float* src = msg_w + n * D;
        for (int k = lane; k < 288; k += 64)
            out[k] = f2bf(k < D ? src[k] : 0.f);
        return;
    }
    row -= 128;
    if (row < 544) {                              // wrz [544][416]
        const int g = row;
        const int gi = (g < 272) ? 0 : 1;
        const int d = g - gi * 272;
        short* out = wrz + g * 416;
        if (d < D) {
            const int r = gi * D + d;
            const float* sih = w_ih + r * MSG;
            const float* shh = w_hh + r * D - 128;     // index by k directly
            for (int k = lane; k < 416; k += 64) {
                float v;
                if (k < 128)            v = sih[k];
                else if (k < 128 + D)   v = shh[k];
                else                    v = 0.f;
                out[k] = f2bf(v);
            }
        } else {
            for (int k = lane; k < 416; k += 64) out[k] = 0;
        }
        return;
    }
    row -= 544;
    if (row < 272) {                              // wxn [272][128]
        const int d = row;
        short* out = wxn + d * 128;
        const float* src = w_ih + (2 * D + d) * MSG;
        for (int k = lane; k < 128; k += 64)
            out[k] = f2bf(d < D ? src[k] : 0.f);
        return;
    }
    row -= 272;
    if (row < 272) {                              // whn [272][288]
        const int d = row;
        short* out = whn + d * 288;
        const float* src = w_hh + (2 * D + d) * D;
        for (int k = lane; k < 288; k += 64)
            out[k] = f2bf((d < D && k < D) ? src[k] : 0.f);
        return;
    }
    row -= 272;
    if (row < 128) {                              // wro [128][288]
        const int n = row;
        short* out = wro + n * 288;
        const float* src = ro_w1 + n * D;
        for (int k = lane; k < 288; k += 64)
            out[k] = f2bf(k < D ? src[k] : 0.f);
        return;
    }
    row -= 128;
    if (row < 16) {                               // wro2 [16][128]
        const int n = row;
        short* out = wro2 + n * 128;
        const float* src = ro_w2 + n * MSG;
        for (int k = lane; k < 128; k += 64)
            out[k] = f2bf(n < NCLS ? src[k] : 0.f);
        return;
    }
    row -= 16;
    {                                             // gate biases [4][272]
        const int seg = row;
        float* out = gb + seg * 272;
        for (int d = lane; d < 272; d += 64) {
            float v = 0.f;
            if (d < D) {
                if (seg == 0)      v = b_ih[d] + b_hh[d];
                else if (seg == 1) v = b_ih[D + d] + b_hh[D + d];
                else if (seg == 2) v = b_ih[2 * D + d];
                else               v = b_hh[2 * D + d];
            }
            out[d] = v;
        }
    }
}

// ---------------------------------------------------------------------------
// fused: one block per graph; full forward in LDS.
// (byte-identical to Round 4's 64.5us version — this round isolates prep)
// 512 threads (8 waves = 2/SIMD block minimum -> VGPR ceiling 256).
//  (1) explicit register staging / rotation of every weight stream so 9-13
//      loads are in flight per K-chain instead of ~1;
//  (2) L2 priming: 10 fire-and-forget 128B-strided touches per wave cover the
//      GRU weight region at kernel start.
// ---------------------------------------------------------------------------
__global__ __launch_bounds__(512, 2) void fused_kernel(
    const float* __restrict__ nodes, const float* __restrict__ pos,
    const int* __restrict__ nrec_g,
    const float* __restrict__ b1g, const float* __restrict__ w2g,
    const float* __restrict__ b2g, const float* __restrict__ msg_bg,
    const float* __restrict__ ro_b1g, const float* __restrict__ ro_b2g,
    const float* __restrict__ ws,
    float* __restrict__ att_out, float* __restrict__ pred)
{
    const short* Wproj = (const short*)(ws + O_WPROJ);
    const short* Wmsg  = (const short*)(ws + O_WMSG);
    const short* Wrz   = (const short*)(ws + O_WRZ);
    const short* Wxn   = (const short*)(ws + O_WXN);
    const short* Whn   = (const short*)(ws + O_WHN);
    const short* Wro   = (const short*)(ws + O_WRO);
    const short* Wro2  = (const short*)(ws + O_WRO2);
    const float* gb    = ws + O_GB;

    __shared__ __align__(16) short bufA[32 * KA_S];
    __shared__ __align__(16) short bufB[32 * KA_S];
    __shared__ __align__(16) short paL[32 * PSTR];
    __shared__ __align__(16) short pbL[32 * PSTR];
    __shared__ __align__(16) short attL[32 * 40];   // bf16 A-layout for mix
    __shared__ __align__(16) short msgT[128 * 40];  // bf16 B^T layout for mix
    __shared__ __align__(16) short hidL[32 * 136];
    __shared__ __align__(16) float b1L[PSTR], w2L[PSTR];

    const int b = blockIdx.x;
    const int tid = threadIdx.x;
    const int wave = tid >> 6, lane = tid & 63;
    const int quad = lane >> 4, lrow = lane & 15;

    // ---- L2 priming: touch Wrz/Wxn/Whn (contiguous ~679 KB) early ----
    floatx4 prm[10];
    {
        const floatx4* pb = (const floatx4*)(ws + O_WRZ);
        const int base = wave * 64 + lane;
#pragma unroll
        for (int p = 0; p < 10; ++p)
            prm[p] = pb[(p * 512 + base) * 8];      // 8 floatx4 = 128 B stride
    }
    // ---- prefetch P1 tile-'wave' weights (hides under P0) ----
    short8 wvA[9];
    {
        const short* bw = Wproj + (wave * 16 + lrow) * KHW + quad * 8;
#pragma unroll
        for (int kk = 0; kk < 9; ++kk) wvA[kk] = *(const short8*)(bw + kk * 32);
    }

    const int nr = nrec_g[b];

    // ---- P0: load h0 bf16, zero pads, stage padded b1/w2 ----
    for (int idx = tid; idx < 32 * 64; idx += 512) {          // nodes (float4)
        int w = idx >> 6, c4 = idx & 63;
        floatx4 v = *(const floatx4*)(nodes + ((size_t)(b * 32 + w)) * FEAT + c4 * 4);
        short4v s; s[0] = f2bf(v[0]); s[1] = f2bf(v[1]); s[2] = f2bf(v[2]); s[3] = f2bf(v[3]);
        *(short4v*)(bufA + w * KA_S + 128 + c4 * 4) = s;
    }
    for (int idx = tid; idx < 32 * POSD; idx += 512) {        // pos
        int w = idx / POSD, c = idx % POSD;
        bufA[w * KA_S + 128 + FEAT + c] = f2bf(pos[((size_t)(b * 32 + w)) * POSD + c]);
    }
    for (int idx = tid; idx < 32 * 34; idx += 512) {          // col pads 390..423
        int w = idx / 34, c = idx % 34;
        bufA[w * KA_S + 390 + c] = 0;
        bufB[w * KA_S + 390 + c] = 0;
    }
    for (int idx = tid; idx < 32 * (PSTR - D); idx += 512) {  // pa/pb pads 262..319
        int w = idx / (PSTR - D), c = idx % (PSTR - D);
        paL[w * PSTR + D + c] = 0;
        pbL[w * PSTR + D + c] = 0;
    }
    for (int d = tid; d < PSTR; d += 512) {
        b1L[d] = (d < D) ? b1g[d] : 0.f;
        w2L[d] = (d < D) ? w2g[d] : 0.f;
    }
    // keep priming loads alive (and let their latency overlap P0's work)
#pragma unroll
    for (int p = 0; p < 10; ++p) asm volatile("" :: "v"(prm[p]));
    __syncthreads();

    // ---- P1: combined GEMM over h0 (tiles 0..32 proj, 33..40 round-0 msg) ----
    {
        auto store_proj = [&](int s, floatx4 acc0, floatx4 acc1) {
            int col = s * 16 + lrow;
#pragma unroll
            for (int rr = 0; rr < 4; ++rr) {
                int r0 = quad * 4 + rr;
                if (col < D) {
                    paL[r0 * PSTR + col] = f2bf(acc0[rr]);
                    paL[(r0 + 16) * PSTR + col] = f2bf(acc1[rr]);
                } else if (col < 2 * D) {
                    pbL[r0 * PSTR + (col - D)] = f2bf(acc0[rr]);
                    pbL[(r0 + 16) * PSTR + (col - D)] = f2bf(acc1[rr]);
                }
            }
        };
        auto store_msg = [&](int s, floatx4 acc0, floatx4 acc1) {
            int col = (s - 33) * 16 + lrow;
            float bias = msg_bg[col];
#pragma unroll
            for (int rr = 0; rr < 4; ++rr) {
                msgT[col * 40 + quad * 4 + rr] = f2bf(acc0[rr] + bias);
                msgT[col * 40 + 16 + quad * 4 + rr] = f2bf(acc1[rr] + bias);
            }
        };
        const short* ap = bufA + lrow * KA_S + 128 + quad * 8;
        short8 wvB[9];

#define P1_LOAD(DST, TT) do { \
            const short* bw_ = ((TT) < 33) \
                ? Wproj + ((TT) * 16 + lrow) * KHW + quad * 8 \
                : Wmsg + (((TT) - 33) * 16 + lrow) * KHW + quad * 8; \
            _Pragma("unroll") \
            for (int kk = 0; kk < 9; ++kk) DST[kk] = *(const short8*)(bw_ + kk * 32); \
        } while (0)

#define P1_TILE(W, TT) do { \
            floatx4 acc0_ = {}, acc1_ = {}; \
            _Pragma("unroll") \
            for (int kk = 0; kk < 9; ++kk) { \
                short8 x0 = *(const short8*)(ap + kk * 32); \
                short8 x1 = *(const short8*)(ap + 16 * KA_S + kk * 32); \
                acc0_ = MFMA(x0, W[kk], acc0_, 0, 0, 0); \
                acc1_ = MFMA(x1, W[kk], acc1_, 0, 0, 0); \
            } \
            if ((TT) < 33) store_proj((TT), acc0_, acc1_); \
            else store_msg((TT), acc0_, acc1_); \
        } while (0)

        int t = wave;                       // 0..7
        P1_LOAD(wvB, t + 8);                // stage next while computing current
        P1_TILE(wvA, t);
        t += 8;                             // 8..15
        P1_LOAD(wvA, t + 8);
        P1_TILE(wvB, t);
        t += 8;                             // 16..23
        P1_LOAD(wvB, t + 8);
        P1_TILE(wvA, t);
        t += 8;                             // 24..31
        P1_LOAD(wvA, t + 8);                // 32..39: always valid
        P1_TILE(wvB, t);
        t += 8;                             // 32..39
        if (t + 8 < 41) P1_LOAD(wvB, t + 8);  // only wave 0 stages tile 40
        P1_TILE(wvA, t);
        t += 8;                             // 40 for wave 0
        if (t < 41) P1_TILE(wvB, t);
#undef P1_LOAD
#undef P1_TILE
    }
    __syncthreads();

    // ---- P2: attention — 32 groups of 16 lanes, 32 j's each ----
    {
        const int grp = tid >> 4;          // i = grp (0..31)
        const int c16 = tid & 15;
        const float b2v = b2g[0];
        float pav[5][4], b1v[5][4], w2v[5][4];
#pragma unroll
        for (int k = 0; k < 5; ++k) {
            int dbase = c16 * 4 + 64 * k;
            short4v p = *(const short4v*)(paL + grp * PSTR + dbase);
            floatx4 bb = *(const floatx4*)(b1L + dbase);
            floatx4 ww = *(const floatx4*)(w2L + dbase);
#pragma unroll
            for (int e = 0; e < 4; ++e) {
                pav[k][e] = bf2f(p[e]); b1v[k][e] = bb[e]; w2v[k][e] = ww[e];
            }
        }
        // c0 = invalid-pair logit
        float p0 = 0.f;
#pragma unroll
        for (int k = 0; k < 5; ++k)
#pragma unroll
            for (int e = 0; e < 4; ++e)
                p0 += fmaxf(b1v[k][e], 0.f) * w2v[k][e];
        p0 += __shfl_down(p0, 8, 16); p0 += __shfl_down(p0, 4, 16);
        p0 += __shfl_down(p0, 2, 16); p0 += __shfl_down(p0, 1, 16);
        float c0 = sigf(p0 + b2v);
        const bool vi = grp < nr;
        for (int j = 0; j < 32; ++j) {
            float a;
            if (j < nr && vi) {
                const short* pb = pbL + j * PSTR + c16 * 4;
                float s = 0.f;
#pragma unroll
                for (int k = 0; k < 5; ++k) {
                    short4v q = *(const short4v*)(pb + 64 * k);
#pragma unroll
                    for (int e = 0; e < 4; ++e) {
                        float v = pav[k][e] + bf2f(q[e]) + b1v[k][e];
                        s += fmaxf(v, 0.f) * w2v[k][e];
                    }
                }
                s += __shfl_down(s, 8, 16); s += __shfl_down(s, 4, 16);
                s += __shfl_down(s, 2, 16); s += __shfl_down(s, 1, 16);
                a = sigf(s + b2v);
            } else {
                a = c0;
            }
            if (c16 == 0) {
                att_out[((size_t)(b * 32 + grp)) * 32 + j] = a;
                attL[grp * 40 + j] = f2bf((j < nr) ? a : 0.f);
            }
        }
    }
    __syncthreads();

    // ---- two message-passing rounds ----
    for (int rnd = 0; rnd < 2; ++rnd) {
        short* src = rnd ? bufB : bufA;
        short* dst = rnd ? bufA : bufB;

        // msg = h @ Wmsg^T + msg_b -> msgT bf16 (round 0 done in P1)
        if (rnd) {
            int s = wave;
            const short* bw = Wmsg + (s * 16 + lrow) * KHW + quad * 8;
            short8 wm[9];
#pragma unroll
            for (int kk = 0; kk < 9; ++kk) wm[kk] = *(const short8*)(bw + kk * 32);
            floatx4 acc0 = {}, acc1 = {};
            const short* ap = src + lrow * KA_S + 128 + quad * 8;
#pragma unroll
            for (int kk = 0; kk < 9; ++kk) {
                short8 x0 = *(const short8*)(ap + kk * 32);
                short8 x1 = *(const short8*)(ap + 16 * KA_S + kk * 32);
                acc0 = MFMA(x0, wm[kk], acc0, 0, 0, 0);
                acc1 = MFMA(x1, wm[kk], acc1, 0, 0, 0);
            }
            int col = s * 16 + lrow;
            float bias = msg_bg[col];
#pragma unroll
            for (int rr = 0; rr < 4; ++rr) {
                msgT[col * 40 + quad * 4 + rr] = f2bf(acc0[rr] + bias);
                msgT[col * 40 + 16 + quad * 4 + rr] = f2bf(acc1[rr] + bias);
            }
            __syncthreads();
        }

        // mix via MFMA: mv = attL(32x32) @ msg -> bf16 src cols 0..127
        {
            int mi = wave & 1, ng = wave >> 1;
            short8 afrag = *(const short8*)(attL + (mi * 16 + lrow) * 40 + quad * 8);
            floatx4 acc0 = {}, acc1 = {};
            short8 bf0 = *(const short8*)(msgT + (ng * 32 + lrow) * 40 + quad * 8);
            short8 bf1 = *(const short8*)(msgT + (ng * 32 + 16 + lrow) * 40 + quad * 8);
            acc0 = MFMA(afrag, bf0, acc0, 0, 0, 0);
            acc1 = MFMA(afrag, bf1, acc1, 0, 0, 0);
#pragma unroll
            for (int rr = 0; rr < 4; ++rr) {
                int m = mi * 16 + quad * 4 + rr;
                src[m * KA_S + ng * 32 + lrow] = f2bf(acc0[rr]);
                src[m * KA_S + ng * 32 + 16 + lrow] = f2bf(acc1[rr]);
            }
        }
        __syncthreads();

        // GRU: fused [gx|gh] GEMM + elementwise, writes dst h-cols.
        for (int s = wave; s < 17; s += 8) {
            const short* ap0 = src + lrow * KA_S + quad * 8;
            const short* ap1 = ap0 + 16 * KA_S;
            const short* bpr = Wrz + (s * 16 + lrow) * KFULL + quad * 8;
            const short* bpz = bpr + 272 * KFULL;
            const short* bpx = Wxn + (s * 16 + lrow) * 128 + quad * 8;
            const short* bph = Whn + (s * 16 + lrow) * KHW + quad * 8;

            short8 wr[13];
#pragma unroll
            for (int kk = 0; kk < 13; ++kk) wr[kk] = *(const short8*)(bpr + kk * 32);

            floatx4 aR0 = {}, aR1 = {}, aZ0 = {}, aZ1 = {};
            floatx4 aN0 = {}, aN1 = {}, aH0 = {}, aH1 = {};
#pragma unroll
            for (int kk = 0; kk < 13; ++kk) {           // r (+x inline); stage z
                short8 x0 = *(const short8*)(ap0 + kk * 32);
                short8 x1 = *(const short8*)(ap1 + kk * 32);
                aR0 = MFMA(x0, wr[kk], aR0, 0, 0, 0);
                aR1 = MFMA(x1, wr[kk], aR1, 0, 0, 0);
                if (kk < 4) {
                    short8 bx = *(const short8*)(bpx + kk * 32);
                    aN0 = MFMA(x0, bx, aN0, 0, 0, 0);
                    aN1 = MFMA(x1, bx, aN1, 0, 0, 0);
                }
                wr[kk] = *(const short8*)(bpz + kk * 32);
            }
#pragma unroll
            for (int kk = 0; kk < 13; ++kk) {           // z chain; stage h
                short8 x0 = *(const short8*)(ap0 + kk * 32);
                short8 x1 = *(const short8*)(ap1 + kk * 32);
                aZ0 = MFMA(x0, wr[kk], aZ0, 0, 0, 0);
                aZ1 = MFMA(x1, wr[kk], aZ1, 0, 0, 0);
                if (kk < 9) wr[kk] = *(const short8*)(bph + kk * 32);
            }
#pragma unroll
            for (int kk = 0; kk < 9; ++kk) {            // h chain
                short8 x0 = *(const short8*)(ap0 + (4 + kk) * 32);
                short8 x1 = *(const short8*)(ap1 + (4 + kk) * 32);
                aH0 = MFMA(x0, wr[kk], aH0, 0, 0, 0);
                aH1 = MFMA(x1, wr[kk], aH1, 0, 0, 0);
            }

            int d = s * 16 + lrow;
            if (d < D) {
                float bgr = gb[d], bgz = gb[272 + d];
                float bxv = gb[544 + d], bhv = gb[816 + d];
#pragma unroll
                for (int i = 0; i < 2; ++i) {
                    floatx4 vR = i ? aR1 : aR0, vZ = i ? aZ1 : aZ0;
                    floatx4 vN = i ? aN1 : aN0, vH = i ? aH1 : aH0;
#pragma unroll
                    for (int rr = 0; rr < 4; ++rr) {
                        int m = i * 16 + quad * 4 + rr;
                        float rg = sigf(vR[rr] + bgr);
                        float zg = sigf(vZ[rr] + bgz);
                        float cg = tanh_fast(vN[rr] + bxv + rg * (vH[rr] + bhv));
                        float hold = bf2f(src[m * KA_S + 128 + d]);
                        float hv = (1.f - zg) * cg + zg * hold;
                        if (m >= nr) hv = 0.f;
                        dst[m * KA_S + 128 + d] = f2bf(hv);
                    }
                }
            }
        }
        __syncthreads();
    }

    // ---- readout: hid = relu(h2 @ Wro^T + ro_b1), h2 in bufA ----
    {
        int s = wave;
        const short* bw = Wro + (s * 16 + lrow) * KHW + quad * 8;
        short8 wv[9];
#pragma unroll
        for (int kk = 0; kk < 9; ++kk) wv[kk] = *(const short8*)(bw + kk * 32);
        floatx4 acc0 = {}, acc1 = {};
        const short* ap = bufA + lrow * KA_S + 128 + quad * 8;
#pragma unroll
        for (int kk = 0; kk < 9; ++kk) {
            short8 x0 = *(const short8*)(ap + kk * 32);
            short8 x1 = *(const short8*)(ap + 16 * KA_S + kk * 32);
            acc0 = MFMA(x0, wv[kk], acc0, 0, 0, 0);
            acc1 = MFMA(x1, wv[kk], acc1, 0, 0, 0);
        }
        int col = s * 16 + lrow;
        float bias = ro_b1g[col];
#pragma unroll
        for (int rr = 0; rr < 4; ++rr) {
            hidL[(quad * 4 + rr) * 136 + col] = f2bf(fmaxf(acc0[rr] + bias, 0.f));
            hidL[(16 + quad * 4 + rr) * 136 + col] = f2bf(fmaxf(acc1[rr] + bias, 0.f));
        }
    }
    __syncthreads();

    // ---- final: pred = hid @ ro_w2^T + ro_b2 (wave 0 only) ----
    if (wave == 0) {
        const short* bw = Wro2 + lrow * 128 + quad * 8;
        short8 wv[4];
#pragma unroll
        for (int kk = 0; kk < 4; ++kk) wv[kk] = *(const short8*)(bw + kk * 32);
        floatx4 acc0 = {}, acc1 = {};
        const short* ap = hidL + lrow * 136 + quad * 8;
#pragma unroll
        for (int kk = 0; kk < 4; ++kk) {
            short8 x0 = *(const short8*)(ap + kk * 32);
            short8 x1 = *(const short8*)(ap + 16 * 136 + kk * 32);
            acc0 = MFMA(x0, wv[kk], acc0, 0, 0, 0);
            acc1 = MFMA(x1, wv[kk], acc1, 0, 0, 0);
        }
        int q = lrow;
        if (q < NCLS) {
            float bias = ro_b2g[q];
#pragma unroll
            for (int i = 0; i < 2; ++i) {
#pragma unroll
                for (int rr = 0; rr < 4; ++rr) {
                    int m = i * 16 + quad * 4 + rr;
                    float v = (i ? acc1[rr] : acc0[rr]) + bias;
                    if (m >= nr) v = 0.f;
                    pred[((size_t)(b * 32 + m)) * NCLS + q] = v;
                }
            }
        }
    }
}

// ---------------------------------------------------------------------------
extern "C" void kernel_launch(void* const* d_in, const int* in_sizes, int n_in,
                              void* d_out, int out_size, void* d_ws, size_t ws_size,
                              hipStream_t stream)
{
    const float* nodes = (const float*)d_in[0];
    const float* pos   = (const float*)d_in[1];
    const int*   nrec  = (const int*)d_in[2];
    const float* w1    = (const float*)d_in[3];
    const float* b1    = (const float*)d_in[4];
    const float* w2    = (const float*)d_in[5];
    const float* b2    = (const float*)d_in[6];
    const float* msg_w = (const float*)d_in[7];
    const float* msg_b = (const float*)d_in[8];
    const float* w_ih  = (const float*)d_in[9];
    const float* w_hh  = (const float*)d_in[10];
    const float* b_ih  = (const float*)d_in[11];
    const float* b_hh  = (const float*)d_in[12];
    const float* ro_w1 = (const float*)d_in[13];
    const float* ro_b1 = (const float*)d_in[14];
    const float* ro_w2 = (const float*)d_in[15];
    const float* ro_b2 = (const float*)d_in[16];
    float* ws   = (float*)d_ws;
    float* pred = (float*)d_out;
    float* attout = pred + (size_t)N_G * M_N * NCLS;

    prep_kernel<<<473, 256, 0, stream>>>(w1, msg_w, w_ih, w_hh, ro_w1, ro_w2,
                                         b_ih, b_hh, ws);
    fused_kernel<<<N_G, 512, 0, stream>>>(nodes, pos, nrec, b1, w2, b2, msg_b,
                                          ro_b1, ro_b2, ws, attout, pred);
}